// Round 1
// baseline (7902.964 us; speedup 1.0000x reference)
//
#include <hip/hip_runtime.h>
#include <stdint.h>

#define NBATCH 64
#define TENC   1024
#define TDEC   256
#define FDIM   8
#define UDIM   256
#define GDIM   1024
#define NHEAD  8
#define DHEAD  32
#define LNEPS  1e-5f

typedef unsigned int   u32;
typedef unsigned short u16;

__device__ __forceinline__ float bf2f_lo(u32 w) { return __uint_as_float(w << 16); }
__device__ __forceinline__ float bf2f_hi(u32 w) { return __uint_as_float(w & 0xFFFF0000u); }
__device__ __forceinline__ u16 f2bf(float f) {
  u32 u = __float_as_uint(f);
  u = (u + 0x7FFFu + ((u >> 16) & 1u)) >> 16;
  return (u16)u;
}
__device__ __forceinline__ float sigf(float x) { return 1.0f / (1.0f + __expf(-x)); }
__device__ __forceinline__ float tanhf_fast(float x) {
  float ax = fabsf(x);
  float e  = __expf(2.0f * ax);          // inf ok
  float r  = 1.0f - 2.0f / (e + 1.0f);   // -> 1 for large ax
  return copysignf(r, x);
}

// ---------------- LayerNorm over F=8 (encoder input) ----------------
__global__ __launch_bounds__(256)
void k_ln8(const float* __restrict__ x, const float* __restrict__ g,
           const float* __restrict__ bt, float* __restrict__ y, int rows) {
  int r = blockIdx.x * blockDim.x + threadIdx.x;
  if (r >= rows) return;
  const float* xp = x + (size_t)r * 8;
  float4 a = ((const float4*)xp)[0];
  float4 b4 = ((const float4*)xp)[1];
  float v[8] = {a.x, a.y, a.z, a.w, b4.x, b4.y, b4.z, b4.w};
  float m = 0.f;
#pragma unroll
  for (int i = 0; i < 8; ++i) m += v[i];
  m *= 0.125f;
  float var = 0.f;
#pragma unroll
  for (int i = 0; i < 8; ++i) { float d = v[i] - m; var += d * d; }
  var *= 0.125f;
  float rs = rsqrtf(var + LNEPS);
  float o[8];
#pragma unroll
  for (int i = 0; i < 8; ++i) o[i] = g[i] * (v[i] - m) * rs + bt[i];
  float* yp = y + (size_t)r * 8;
  ((float4*)yp)[0] = make_float4(o[0], o[1], o[2], o[3]);
  ((float4*)yp)[1] = make_float4(o[4], o[5], o[6], o[7]);
}

// ---------------- pack U [256,1024] f32 -> bf16, layout [kg=32][j=1024][kk=8] ----------------
__global__ __launch_bounds__(256)
void k_packU(const float* __restrict__ U, u16* __restrict__ Upk) {
  int idx = blockIdx.x * 256 + threadIdx.x;  // 0..262143
  int k = idx >> 10, j = idx & 1023;
  float v = U[idx];
  Upk[(size_t)(((k >> 3) << 10) + j) * 8 + (k & 7)] = f2bf(v);
}

// ---------------- LSTM scan: one block per batch element ----------------
__global__ __launch_bounds__(1024)
void k_scan(const float* __restrict__ xseq,   // [B, T, 8]
            const float* __restrict__ Wmat,   // [8, 1024]
            const uint4* __restrict__ Upk,    // [32*1024] x (8 bf16)
            const float* __restrict__ bias,   // [1024]
            const float* __restrict__ h0,     // [B,256] or null
            const float* __restrict__ c0,     // [B,256] or null
            float* __restrict__ seq_out,      // [B,T,256]
            float* __restrict__ hT, float* __restrict__ cT,  // [B,256] or null
            int T) {
  __shared__ __align__(16) float Wl[8 * 1024];
  __shared__ __align__(16) float hl[256];
  __shared__ __align__(16) float zl[1024];
  const int j = threadIdx.x, b = blockIdx.x;
  for (int i = j; i < 8192; i += 1024) Wl[i] = Wmat[i];
  const float bj = bias[j];
  float c_reg = 0.f;
  if (j < 256) {
    hl[j] = h0 ? h0[b * 256 + j] : 0.f;
    if (c0) c_reg = c0[b * 256 + j];
  }
  __syncthreads();
  const uint4* up = Upk + j;
  for (int t = 0; t < T; ++t) {
    const float* xp = xseq + (size_t)(b * T + t) * 8;
    float4 xa = ((const float4*)xp)[0];
    float4 xb = ((const float4*)xp)[1];
    float acc = bj
      + xa.x * Wl[j]        + xa.y * Wl[1024 + j] + xa.z * Wl[2048 + j] + xa.w * Wl[3072 + j]
      + xb.x * Wl[4096 + j] + xb.y * Wl[5120 + j] + xb.z * Wl[6144 + j] + xb.w * Wl[7168 + j];
#pragma unroll 8
    for (int kg = 0; kg < 32; ++kg) {
      uint4 w = up[kg << 10];
      float4 ha = *(const float4*)(hl + (kg << 3));
      float4 hb = *(const float4*)(hl + (kg << 3) + 4);
      acc += bf2f_lo(w.x) * ha.x + bf2f_hi(w.x) * ha.y
           + bf2f_lo(w.y) * ha.z + bf2f_hi(w.y) * ha.w
           + bf2f_lo(w.z) * hb.x + bf2f_hi(w.z) * hb.y
           + bf2f_lo(w.w) * hb.z + bf2f_hi(w.w) * hb.w;
    }
    zl[j] = acc;
    __syncthreads();
    if (j < 256) {
      float ig = sigf(zl[j]);
      float fg = sigf(zl[256 + j]);
      float gg = tanhf_fast(zl[512 + j]);
      float og = sigf(zl[768 + j]);
      c_reg = fg * c_reg + ig * gg;
      float h = og * tanhf_fast(c_reg);
      hl[j] = h;
      seq_out[(size_t)(b * T + t) * 256 + j] = h;
    }
    __syncthreads();
  }
  if (hT && j < 256) { hT[b * 256 + j] = hl[j]; cT[b * 256 + j] = c_reg; }
}

// ---------------- GEMM: C[M,256] = A[M,256] @ B[256,256] + bias ----------------
// OMODE 0: plain f32 [M,256]. OMODE 1: scatter f32 [b,h,t,d]. OMODE 2: scatter bf16 [b,h,t,d].
template <int OMODE>
__global__ __launch_bounds__(256)
void k_gemm256(const float* __restrict__ A, const float* __restrict__ Bw,
               const float* __restrict__ bias, void* __restrict__ outp,
               int M, int Tdim) {
  __shared__ __align__(16) float As[16][68];
  __shared__ __align__(16) float Bs[16][68];
  const int tid = threadIdx.x;
  const int tx = tid & 15, ty = tid >> 4;
  const int bm = blockIdx.x * 64, bn = blockIdx.y * 64;
  const int ar = tid >> 2, ac = (tid & 3) << 2;
  const int br = tid >> 4, bc = (tid & 15) << 2;
  float acc[4][4] = {};
  for (int k0 = 0; k0 < 256; k0 += 16) {
    float4 av = *(const float4*)(A + (size_t)(bm + ar) * 256 + k0 + ac);
    As[ac + 0][ar] = av.x; As[ac + 1][ar] = av.y;
    As[ac + 2][ar] = av.z; As[ac + 3][ar] = av.w;
    float4 bv = *(const float4*)(Bw + (size_t)(k0 + br) * 256 + bn + bc);
    *(float4*)&Bs[br][bc] = bv;
    __syncthreads();
#pragma unroll
    for (int k = 0; k < 16; ++k) {
      float4 a4 = *(const float4*)&As[k][ty << 2];
      float4 b4 = *(const float4*)&Bs[k][tx << 2];
      float aa[4] = {a4.x, a4.y, a4.z, a4.w};
      float bb[4] = {b4.x, b4.y, b4.z, b4.w};
#pragma unroll
      for (int i = 0; i < 4; ++i)
#pragma unroll
        for (int jj = 0; jj < 4; ++jj)
          acc[i][jj] = fmaf(aa[i], bb[jj], acc[i][jj]);
    }
    __syncthreads();
  }
#pragma unroll
  for (int i = 0; i < 4; ++i) {
    int m = bm + (ty << 2) + i;
#pragma unroll
    for (int jj = 0; jj < 4; ++jj) {
      int n = bn + (tx << 2) + jj;
      float v = acc[i][jj] + bias[n];
      if (OMODE == 0) {
        ((float*)outp)[(size_t)m * 256 + n] = v;
      } else {
        int bb_ = m / Tdim, t = m % Tdim;
        int hh = n >> 5, dd = n & 31;
        size_t o = ((((size_t)bb_ * NHEAD + hh) * Tdim) + t) * 32 + dd;
        if (OMODE == 1) ((float*)outp)[o] = v;
        else            ((u16*)outp)[o]   = f2bf(v);
      }
    }
  }
}

// ---------------- attention: one block per (b,h); thread = q row ----------------
__global__ __launch_bounds__(256)
void k_attn(const float* __restrict__ Q, const u16* __restrict__ Kb,
            const u16* __restrict__ Vb, float* __restrict__ ctx) {
  const int bh = blockIdx.x;
  const int b = bh >> 3, h = bh & 7;
  const int tid = threadIdx.x;
  __shared__ __align__(16) float Kl[64][36];
  __shared__ __align__(16) float Vl[64][36];
  float q[32];
  {
    const float* qp = Q + ((size_t)bh * TDEC + tid) * 32;
#pragma unroll
    for (int i = 0; i < 8; ++i) {
      float4 v = ((const float4*)qp)[i];
      q[i * 4 + 0] = v.x * 0.17677669529663687f;
      q[i * 4 + 1] = v.y * 0.17677669529663687f;
      q[i * 4 + 2] = v.z * 0.17677669529663687f;
      q[i * 4 + 3] = v.w * 0.17677669529663687f;
    }
  }
  float mrun = -3.0e38f, lrun = 0.f;
  float acc[32];
#pragma unroll
  for (int i = 0; i < 32; ++i) acc[i] = 0.f;
  const int lr = tid >> 2, lc = (tid & 3) << 3;
  for (int kt = 0; kt < TENC; kt += 64) {
    {
      uint4 kw = *(const uint4*)(Kb + ((size_t)bh * TENC + kt + lr) * 32 + lc);
      Kl[lr][lc + 0] = bf2f_lo(kw.x); Kl[lr][lc + 1] = bf2f_hi(kw.x);
      Kl[lr][lc + 2] = bf2f_lo(kw.y); Kl[lr][lc + 3] = bf2f_hi(kw.y);
      Kl[lr][lc + 4] = bf2f_lo(kw.z); Kl[lr][lc + 5] = bf2f_hi(kw.z);
      Kl[lr][lc + 6] = bf2f_lo(kw.w); Kl[lr][lc + 7] = bf2f_hi(kw.w);
      uint4 vw = *(const uint4*)(Vb + ((size_t)bh * TENC + kt + lr) * 32 + lc);
      Vl[lr][lc + 0] = bf2f_lo(vw.x); Vl[lr][lc + 1] = bf2f_hi(vw.x);
      Vl[lr][lc + 2] = bf2f_lo(vw.y); Vl[lr][lc + 3] = bf2f_hi(vw.y);
      Vl[lr][lc + 4] = bf2f_lo(vw.z); Vl[lr][lc + 5] = bf2f_hi(vw.z);
      Vl[lr][lc + 6] = bf2f_lo(vw.w); Vl[lr][lc + 7] = bf2f_hi(vw.w);
    }
    __syncthreads();
#pragma unroll
    for (int cch = 0; cch < 8; ++cch) {
      float s8[8];
#pragma unroll
      for (int i = 0; i < 8; ++i) {
        const float4* kr = (const float4*)&Kl[cch * 8 + i][0];
        float ss = 0.f;
#pragma unroll
        for (int d4 = 0; d4 < 8; ++d4) {
          float4 kv = kr[d4];
          ss = fmaf(q[d4 * 4 + 0], kv.x, ss);
          ss = fmaf(q[d4 * 4 + 1], kv.y, ss);
          ss = fmaf(q[d4 * 4 + 2], kv.z, ss);
          ss = fmaf(q[d4 * 4 + 3], kv.w, ss);
        }
        s8[i] = ss;
      }
      float mnew = mrun;
#pragma unroll
      for (int i = 0; i < 8; ++i) mnew = fmaxf(mnew, s8[i]);
      float sc = __expf(mrun - mnew);
      mrun = mnew;
      lrun *= sc;
#pragma unroll
      for (int d = 0; d < 32; ++d) acc[d] *= sc;
#pragma unroll
      for (int i = 0; i < 8; ++i) {
        float p = __expf(s8[i] - mnew);
        lrun += p;
        const float4* vr = (const float4*)&Vl[cch * 8 + i][0];
#pragma unroll
        for (int d4 = 0; d4 < 8; ++d4) {
          float4 vv = vr[d4];
          acc[d4 * 4 + 0] = fmaf(p, vv.x, acc[d4 * 4 + 0]);
          acc[d4 * 4 + 1] = fmaf(p, vv.y, acc[d4 * 4 + 1]);
          acc[d4 * 4 + 2] = fmaf(p, vv.z, acc[d4 * 4 + 2]);
          acc[d4 * 4 + 3] = fmaf(p, vv.w, acc[d4 * 4 + 3]);
        }
      }
    }
    __syncthreads();
  }
  float inv = 1.0f / lrun;
  float* op = ctx + ((size_t)(b * TDEC + tid) * 256 + h * 32);
#pragma unroll
  for (int i = 0; i < 8; ++i) {
    ((float4*)op)[i] = make_float4(acc[i * 4 + 0] * inv, acc[i * 4 + 1] * inv,
                                   acc[i * 4 + 2] * inv, acc[i * 4 + 3] * inv);
  }
}

// ---------------- final: LN(dec_seq + ctxo) @ W_out + b_out ----------------
__global__ __launch_bounds__(256)
void k_final(const float* __restrict__ dec_seq, const float* __restrict__ ctxo,
             const float* __restrict__ g, const float* __restrict__ bb,
             const float* __restrict__ Wout, const float* __restrict__ bout,
             float* __restrict__ out) {
  const int wv = threadIdx.x >> 6, lane = threadIdx.x & 63;
  const int row = blockIdx.x * 4 + wv;
  const size_t base = (size_t)row * 256 + lane * 4;
  float4 dv = *(const float4*)(dec_seq + base);
  float4 cv = *(const float4*)(ctxo + base);
  float v[4] = {dv.x + cv.x, dv.y + cv.y, dv.z + cv.z, dv.w + cv.w};
  float s = v[0] + v[1] + v[2] + v[3];
#pragma unroll
  for (int off = 32; off >= 1; off >>= 1) s += __shfl_xor(s, off, 64);
  float m = s * (1.0f / 256.0f);
  float d2 = 0.f;
#pragma unroll
  for (int i = 0; i < 4; ++i) { float d = v[i] - m; d2 += d * d; }
#pragma unroll
  for (int off = 32; off >= 1; off >>= 1) d2 += __shfl_xor(d2, off, 64);
  float rs = rsqrtf(d2 * (1.0f / 256.0f) + LNEPS);
  float4 g4 = *(const float4*)(g + lane * 4);
  float4 b4 = *(const float4*)(bb + lane * 4);
  float4 w4 = *(const float4*)(Wout + lane * 4);
  float mix0 = g4.x * (v[0] - m) * rs + b4.x;
  float mix1 = g4.y * (v[1] - m) * rs + b4.y;
  float mix2 = g4.z * (v[2] - m) * rs + b4.z;
  float mix3 = g4.w * (v[3] - m) * rs + b4.w;
  float p = mix0 * w4.x + mix1 * w4.y + mix2 * w4.z + mix3 * w4.w;
#pragma unroll
  for (int off = 32; off >= 1; off >>= 1) p += __shfl_xor(p, off, 64);
  if (lane == 0) out[row] = p + bout[0];
}

extern "C" void kernel_launch(void* const* d_in, const int* in_sizes, int n_in,
                              void* d_out, int out_size, void* d_ws, size_t ws_size,
                              hipStream_t stream) {
  const float* enc_in   = (const float*)d_in[0];
  const float* dec_in   = (const float*)d_in[1];
  const float* ln_enc_g = (const float*)d_in[2];
  const float* ln_enc_b = (const float*)d_in[3];
  const float* W_enc    = (const float*)d_in[4];
  const float* U_enc    = (const float*)d_in[5];
  const float* b_enc    = (const float*)d_in[6];
  const float* W_dec    = (const float*)d_in[7];
  const float* U_dec    = (const float*)d_in[8];
  const float* b_dec    = (const float*)d_in[9];
  const float* Wq = (const float*)d_in[10]; const float* bq = (const float*)d_in[11];
  const float* Wk = (const float*)d_in[12]; const float* bk = (const float*)d_in[13];
  const float* Wv = (const float*)d_in[14]; const float* bv = (const float*)d_in[15];
  const float* Wo = (const float*)d_in[16]; const float* bo = (const float*)d_in[17];
  const float* ln_post_g = (const float*)d_in[18];
  const float* ln_post_b = (const float*)d_in[19];
  const float* W_out     = (const float*)d_in[20];
  const float* b_out     = (const float*)d_in[21];

  char* ws = (char*)d_ws;
  size_t off = 0;
  auto alloc = [&](size_t bytes) -> void* {
    void* p = ws + off;
    off += (bytes + 255) & ~(size_t)255;
    return p;
  };
  float* xln     = (float*)alloc((size_t)NBATCH * TENC * 8 * 4);        // 2 MB
  u16*   upkE    = (u16*)  alloc((size_t)256 * 1024 * 2);               // 0.5 MB
  u16*   upkD    = (u16*)  alloc((size_t)256 * 1024 * 2);               // 0.5 MB
  float* enc_seq = (float*)alloc((size_t)NBATCH * TENC * 256 * 4);      // 64 MB
  float* dec_seq = (float*)alloc((size_t)NBATCH * TDEC * 256 * 4);      // 16 MB
  float* hfin    = (float*)alloc((size_t)NBATCH * 256 * 4);
  float* cfin    = (float*)alloc((size_t)NBATCH * 256 * 4);
  float* Qp      = (float*)alloc((size_t)NBATCH * NHEAD * TDEC * 32 * 4);   // 16 MB
  u16*   Kb      = (u16*)  alloc((size_t)NBATCH * NHEAD * TENC * 32 * 2);   // 33.5 MB
  u16*   Vb      = (u16*)  alloc((size_t)NBATCH * NHEAD * TENC * 32 * 2);   // 33.5 MB
  float* ctx     = (float*)alloc((size_t)NBATCH * TDEC * 256 * 4);      // 16 MB
  float* ctxo    = (float*)alloc((size_t)NBATCH * TDEC * 256 * 4);      // 16 MB

  // 1. LN on encoder input
  k_ln8<<<dim3(256), dim3(256), 0, stream>>>(enc_in, ln_enc_g, ln_enc_b, xln,
                                             NBATCH * TENC);
  // 2. pack recurrent weights to bf16
  k_packU<<<dim3(1024), dim3(256), 0, stream>>>(U_enc, upkE);
  k_packU<<<dim3(1024), dim3(256), 0, stream>>>(U_dec, upkD);
  // 3. encoder scan
  k_scan<<<dim3(NBATCH), dim3(1024), 0, stream>>>(
      xln, W_enc, (const uint4*)upkE, b_enc, nullptr, nullptr, enc_seq, hfin, cfin, TENC);
  // 4. decoder scan (init from encoder final state)
  k_scan<<<dim3(NBATCH), dim3(1024), 0, stream>>>(
      dec_in, W_dec, (const uint4*)upkD, b_dec, hfin, cfin, dec_seq, nullptr, nullptr, TDEC);
  // 5. projections
  k_gemm256<1><<<dim3(256, 4), dim3(256), 0, stream>>>(dec_seq, Wq, bq, Qp, NBATCH * TDEC, TDEC);
  k_gemm256<2><<<dim3(1024, 4), dim3(256), 0, stream>>>(enc_seq, Wk, bk, Kb, NBATCH * TENC, TENC);
  k_gemm256<2><<<dim3(1024, 4), dim3(256), 0, stream>>>(enc_seq, Wv, bv, Vb, NBATCH * TENC, TENC);
  // 6. attention
  k_attn<<<dim3(NBATCH * NHEAD), dim3(256), 0, stream>>>(Qp, Kb, Vb, ctx);
  // 7. output projection
  k_gemm256<0><<<dim3(256, 4), dim3(256), 0, stream>>>(ctx, Wo, bo, ctxo, NBATCH * TDEC, 0x7fffffff);
  // 8. residual + LN + final dot
  k_final<<<dim3(NBATCH * TDEC / 4), dim3(256), 0, stream>>>(
      dec_seq, ctxo, ln_post_g, ln_post_b, W_out, b_out, (float*)d_out);
}

// Round 2
// 3450.317 us; speedup vs baseline: 2.2905x; 2.2905x over previous
//
#include <hip/hip_runtime.h>
#include <stdint.h>

#define NBATCH 64
#define TENC   1024
#define TDEC   256
#define FDIM   8
#define UDIM   256
#define GDIM   1024
#define NHEAD  8
#define DHEAD  32
#define LNEPS  1e-5f

// ext-k = 256 (U rows) + 8 (W rows) = 264 -> 132 f16-pairs, 33 per k-slice
#define KP_TOT 132
#define KP_W   33   // pairs per wave-group (k-slice)
#define KP_V   25   // pairs held in VGPR per thread
#define KP_L   8    // pairs held in LDS per thread

typedef unsigned int   u32;
typedef unsigned short u16;

typedef _Float16 half2v __attribute__((ext_vector_type(2)));

__device__ __forceinline__ float bf2f_lo(u32 w) { return __uint_as_float(w << 16); }
__device__ __forceinline__ float bf2f_hi(u32 w) { return __uint_as_float(w & 0xFFFF0000u); }
__device__ __forceinline__ u16 f2bf(float f) {
  u32 u = __float_as_uint(f);
  u = (u + 0x7FFFu + ((u >> 16) & 1u)) >> 16;
  return (u16)u;
}
__device__ __forceinline__ u16 f2h_bits(float f) {
  _Float16 h = (_Float16)f;
  return __builtin_bit_cast(u16, h);
}
__device__ __forceinline__ float fdot2p(u32 wp, u32 hp, float acc) {
  return __builtin_amdgcn_fdot2(__builtin_bit_cast(half2v, wp),
                                __builtin_bit_cast(half2v, hp), acc, false);
}
__device__ __forceinline__ float sigf(float x) { return 1.0f / (1.0f + __expf(-x)); }
__device__ __forceinline__ float tanhf_fast(float x) {
  float ax = fabsf(x);
  float e  = __expf(2.0f * ax);
  float r  = 1.0f - 2.0f / (e + 1.0f);
  return copysignf(r, x);
}

// ---------------- LayerNorm over F=8 (encoder input) ----------------
__global__ __launch_bounds__(256)
void k_ln8(const float* __restrict__ x, const float* __restrict__ g,
           const float* __restrict__ bt, float* __restrict__ y, int rows) {
  int r = blockIdx.x * blockDim.x + threadIdx.x;
  if (r >= rows) return;
  const float* xp = x + (size_t)r * 8;
  float4 a = ((const float4*)xp)[0];
  float4 b4 = ((const float4*)xp)[1];
  float v[8] = {a.x, a.y, a.z, a.w, b4.x, b4.y, b4.z, b4.w};
  float m = 0.f;
#pragma unroll
  for (int i = 0; i < 8; ++i) m += v[i];
  m *= 0.125f;
  float var = 0.f;
#pragma unroll
  for (int i = 0; i < 8; ++i) { float d = v[i] - m; var += d * d; }
  var *= 0.125f;
  float rs = rsqrtf(var + LNEPS);
  float o[8];
#pragma unroll
  for (int i = 0; i < 8; ++i) o[i] = g[i] * (v[i] - m) * rs + bt[i];
  float* yp = y + (size_t)r * 8;
  ((float4*)yp)[0] = make_float4(o[0], o[1], o[2], o[3]);
  ((float4*)yp)[1] = make_float4(o[4], o[5], o[6], o[7]);
}

// ------- pack [U(256 rows); W(8 rows)] f32 -> f16 pairs: out[kp][c], kp=0..131 -------
__global__ __launch_bounds__(256)
void k_packUW(const float* __restrict__ U, const float* __restrict__ W,
              u32* __restrict__ out) {
  int idx = blockIdx.x * 256 + threadIdx.x;  // 132*1024
  if (idx >= KP_TOT * GDIM) return;
  int kp = idx >> 10, c = idx & 1023;
  int r0 = 2 * kp, r1 = 2 * kp + 1;
  float f0 = (r0 < 256) ? U[(size_t)r0 * GDIM + c] : W[(size_t)(r0 - 256) * GDIM + c];
  float f1 = (r1 < 256) ? U[(size_t)r1 * GDIM + c] : W[(size_t)(r1 - 256) * GDIM + c];
  out[idx] = (u32)f2h_bits(f0) | ((u32)f2h_bits(f1) << 16);
}

// ---------------- LSTM scan v2: register/LDS-resident f16 weights ----------------
// 64 blocks x 1024 threads. Wave w: k-slice ks=w>>2 (33 pairs), col-group cg=w&3.
// Lane owns 4 consecutive cols c0 = cg*256 + lane*4.
#define DOT4(w4, hh)                                              \
  do {                                                            \
    a0 = fdot2p((w4).x, (hh), a0); a1 = fdot2p((w4).y, (hh), a1); \
    a2 = fdot2p((w4).z, (hh), a2); a3 = fdot2p((w4).w, (hh), a3); \
  } while (0)

__global__ __launch_bounds__(1024, 1)
void k_scan2(const float* __restrict__ xseq,  // [B,T,8]
             const u32* __restrict__ Upk,     // [132][1024] f16-pairs
             const float* __restrict__ bias,  // [1024]
             const float* __restrict__ h0, const float* __restrict__ c0,
             float* __restrict__ seq_out,     // [B,T,256]
             float* __restrict__ hT, float* __restrict__ cT, int T) {
  __shared__ __align__(16) uint4 wl[1024 * KP_L];  // 128 KB, swizzled per-thread slices
  __shared__ __align__(16) float zp[4][1024];      // 16 KB k-partials
  __shared__ __align__(16) u32  hpk[4][36];        // ext-h f16 pairs per k-slice (padded)
  __shared__ __align__(16) float biasl[1024];      // 4 KB

  const int tid = threadIdx.x, b = blockIdx.x;
  const int w = tid >> 6, lane = tid & 63;
  const int ks = w >> 2, cg = w & 3;
  const int c0i = cg * 256 + lane * 4;

  // ---- load weights: 25 uint4 -> VGPR, 8 uint4 -> swizzled LDS ----
  const uint4* up = (const uint4*)Upk;
  const int ubase = ks * KP_W * 256 + (c0i >> 2);
  uint4 wv[KP_V];
#pragma unroll
  for (int i = 0; i < KP_V; ++i) wv[i] = up[ubase + i * 256];
  for (int i = 0; i < KP_L; ++i)
    wl[(tid << 3) + (i ^ (lane & 7))] = up[ubase + (KP_V + i) * 256];
  biasl[tid] = bias[tid];

  // ---- per-thread constant slot for writing h as f16 pair halves ----
  const int m = tid >> 1;
  const int hks = (m >= 99) ? 3 : (m >= 66) ? 2 : (m >= 33) ? 1 : 0;
  const int hii = m - hks * KP_W;

  // ---- init state ----
  float c_reg = 0.f, h_last = 0.f;
  if (tid < 256) {
    float hv = h0 ? h0[b * 256 + tid] : 0.f;
    c_reg = c0 ? c0[b * 256 + tid] : 0.f;
    h_last = hv;
    ((u16*)&hpk[hks][hii])[tid & 1] = f2h_bits(hv);
  }
  if (tid < 8) {
    float xv = xseq[(size_t)(b * T + 0) * 8 + tid];
    ((u16*)&hpk[3][29 + (tid >> 1)])[tid & 1] = f2h_bits(xv);
  }
  __syncthreads();

  for (int t = 0; t < T; ++t) {
    // ---- dot phase: z-partials for this k-slice ----
    const u32* hrow = &hpk[ks][0];
    float a0 = 0.f, a1 = 0.f, a2 = 0.f, a3 = 0.f;
#pragma unroll
    for (int ch = 0; ch < 6; ++ch) {  // pairs 0..23 (VGPR weights)
      uint4 hq = *(const uint4*)(hrow + ch * 4);
      DOT4(wv[ch * 4 + 0], hq.x);
      DOT4(wv[ch * 4 + 1], hq.y);
      DOT4(wv[ch * 4 + 2], hq.z);
      DOT4(wv[ch * 4 + 3], hq.w);
    }
    {  // pair 24 (VGPR)
      u32 hh = hrow[24];
      DOT4(wv[24], hh);
    }
#pragma unroll
    for (int jj = 0; jj < KP_L; ++jj) {  // pairs 25..32 (LDS weights)
      uint4 w4 = wl[(tid << 3) + (jj ^ (lane & 7))];
      u32 hh = hrow[KP_V + jj];
      DOT4(w4, hh);
    }
    *(float4*)&zp[ks][c0i] = make_float4(a0, a1, a2, a3);
    __syncthreads();

    // ---- gate phase (4 waves) ----
    if (tid < 256) {
      float zi = biasl[tid] + zp[0][tid] + zp[1][tid] + zp[2][tid] + zp[3][tid];
      float zf = biasl[256 + tid] + zp[0][256 + tid] + zp[1][256 + tid] +
                 zp[2][256 + tid] + zp[3][256 + tid];
      float zg = biasl[512 + tid] + zp[0][512 + tid] + zp[1][512 + tid] +
                 zp[2][512 + tid] + zp[3][512 + tid];
      float zo = biasl[768 + tid] + zp[0][768 + tid] + zp[1][768 + tid] +
                 zp[2][768 + tid] + zp[3][768 + tid];
      float ig = sigf(zi), fg = sigf(zf);
      float gg = tanhf_fast(zg), og = sigf(zo);
      c_reg = fg * c_reg + ig * gg;
      float h = og * tanhf_fast(c_reg);
      h_last = h;
      seq_out[(size_t)(b * T + t) * 256 + tid] = h;
      ((u16*)&hpk[hks][hii])[tid & 1] = f2h_bits(h);
    }
    if (tid < 8) {  // stage x for t+1
      int t2 = (t + 1 < T) ? (t + 1) : (T - 1);
      float xv = xseq[(size_t)(b * T + t2) * 8 + tid];
      ((u16*)&hpk[3][29 + (tid >> 1)])[tid & 1] = f2h_bits(xv);
    }
    __syncthreads();
  }
  if (hT && tid < 256) {
    hT[b * 256 + tid] = h_last;
    cT[b * 256 + tid] = c_reg;
  }
}

// ---------------- GEMM: C[M,256] = A[M,256] @ B[256,256] + bias ----------------
template <int OMODE>
__global__ __launch_bounds__(256)
void k_gemm256(const float* __restrict__ A, const float* __restrict__ Bw,
               const float* __restrict__ bias, void* __restrict__ outp,
               int M, int Tdim) {
  __shared__ __align__(16) float As[16][68];
  __shared__ __align__(16) float Bs[16][68];
  const int tid = threadIdx.x;
  const int tx = tid & 15, ty = tid >> 4;
  const int bm = blockIdx.x * 64, bn = blockIdx.y * 64;
  const int ar = tid >> 2, ac = (tid & 3) << 2;
  const int br = tid >> 4, bc = (tid & 15) << 2;
  float acc[4][4] = {};
  for (int k0 = 0; k0 < 256; k0 += 16) {
    float4 av = *(const float4*)(A + (size_t)(bm + ar) * 256 + k0 + ac);
    As[ac + 0][ar] = av.x; As[ac + 1][ar] = av.y;
    As[ac + 2][ar] = av.z; As[ac + 3][ar] = av.w;
    float4 bv = *(const float4*)(Bw + (size_t)(k0 + br) * 256 + bn + bc);
    *(float4*)&Bs[br][bc] = bv;
    __syncthreads();
#pragma unroll
    for (int k = 0; k < 16; ++k) {
      float4 a4 = *(const float4*)&As[k][ty << 2];
      float4 b4 = *(const float4*)&Bs[k][tx << 2];
      float aa[4] = {a4.x, a4.y, a4.z, a4.w};
      float bb[4] = {b4.x, b4.y, b4.z, b4.w};
#pragma unroll
      for (int i = 0; i < 4; ++i)
#pragma unroll
        for (int jj = 0; jj < 4; ++jj)
          acc[i][jj] = fmaf(aa[i], bb[jj], acc[i][jj]);
    }
    __syncthreads();
  }
#pragma unroll
  for (int i = 0; i < 4; ++i) {
    int mm = bm + (ty << 2) + i;
#pragma unroll
    for (int jj = 0; jj < 4; ++jj) {
      int n = bn + (tx << 2) + jj;
      float v = acc[i][jj] + bias[n];
      if (OMODE == 0) {
        ((float*)outp)[(size_t)mm * 256 + n] = v;
      } else {
        int bb_ = mm / Tdim, t = mm % Tdim;
        int hh = n >> 5, dd = n & 31;
        size_t o = ((((size_t)bb_ * NHEAD + hh) * Tdim) + t) * 32 + dd;
        if (OMODE == 1) ((float*)outp)[o] = v;
        else            ((u16*)outp)[o]   = f2bf(v);
      }
    }
  }
}

// ---------------- attention: one block per (b,h); thread = q row ----------------
__global__ __launch_bounds__(256)
void k_attn(const float* __restrict__ Q, const u16* __restrict__ Kb,
            const u16* __restrict__ Vb, float* __restrict__ ctx) {
  const int bh = blockIdx.x;
  const int b = bh >> 3, h = bh & 7;
  const int tid = threadIdx.x;
  __shared__ __align__(16) float Kl[64][36];
  __shared__ __align__(16) float Vl[64][36];
  float q[32];
  {
    const float* qp = Q + ((size_t)bh * TDEC + tid) * 32;
#pragma unroll
    for (int i = 0; i < 8; ++i) {
      float4 v = ((const float4*)qp)[i];
      q[i * 4 + 0] = v.x * 0.17677669529663687f;
      q[i * 4 + 1] = v.y * 0.17677669529663687f;
      q[i * 4 + 2] = v.z * 0.17677669529663687f;
      q[i * 4 + 3] = v.w * 0.17677669529663687f;
    }
  }
  float mrun = -3.0e38f, lrun = 0.f;
  float acc[32];
#pragma unroll
  for (int i = 0; i < 32; ++i) acc[i] = 0.f;
  const int lr = tid >> 2, lc = (tid & 3) << 3;
  for (int kt = 0; kt < TENC; kt += 64) {
    {
      uint4 kw = *(const uint4*)(Kb + ((size_t)bh * TENC + kt + lr) * 32 + lc);
      Kl[lr][lc + 0] = bf2f_lo(kw.x); Kl[lr][lc + 1] = bf2f_hi(kw.x);
      Kl[lr][lc + 2] = bf2f_lo(kw.y); Kl[lr][lc + 3] = bf2f_hi(kw.y);
      Kl[lr][lc + 4] = bf2f_lo(kw.z); Kl[lr][lc + 5] = bf2f_hi(kw.z);
      Kl[lr][lc + 6] = bf2f_lo(kw.w); Kl[lr][lc + 7] = bf2f_hi(kw.w);
      uint4 vw = *(const uint4*)(Vb + ((size_t)bh * TENC + kt + lr) * 32 + lc);
      Vl[lr][lc + 0] = bf2f_lo(vw.x); Vl[lr][lc + 1] = bf2f_hi(vw.x);
      Vl[lr][lc + 2] = bf2f_lo(vw.y); Vl[lr][lc + 3] = bf2f_hi(vw.y);
      Vl[lr][lc + 4] = bf2f_lo(vw.z); Vl[lr][lc + 5] = bf2f_hi(vw.z);
      Vl[lr][lc + 6] = bf2f_lo(vw.w); Vl[lr][lc + 7] = bf2f_hi(vw.w);
    }
    __syncthreads();
#pragma unroll
    for (int cch = 0; cch < 8; ++cch) {
      float s8[8];
#pragma unroll
      for (int i = 0; i < 8; ++i) {
        const float4* kr = (const float4*)&Kl[cch * 8 + i][0];
        float ss = 0.f;
#pragma unroll
        for (int d4 = 0; d4 < 8; ++d4) {
          float4 kv = kr[d4];
          ss = fmaf(q[d4 * 4 + 0], kv.x, ss);
          ss = fmaf(q[d4 * 4 + 1], kv.y, ss);
          ss = fmaf(q[d4 * 4 + 2], kv.z, ss);
          ss = fmaf(q[d4 * 4 + 3], kv.w, ss);
        }
        s8[i] = ss;
      }
      float mnew = mrun;
#pragma unroll
      for (int i = 0; i < 8; ++i) mnew = fmaxf(mnew, s8[i]);
      float sc = __expf(mrun - mnew);
      mrun = mnew;
      lrun *= sc;
#pragma unroll
      for (int d = 0; d < 32; ++d) acc[d] *= sc;
#pragma unroll
      for (int i = 0; i < 8; ++i) {
        float p = __expf(s8[i] - mnew);
        lrun += p;
        const float4* vr = (const float4*)&Vl[cch * 8 + i][0];
#pragma unroll
        for (int d4 = 0; d4 < 8; ++d4) {
          float4 vv = vr[d4];
          acc[d4 * 4 + 0] = fmaf(p, vv.x, acc[d4 * 4 + 0]);
          acc[d4 * 4 + 1] = fmaf(p, vv.y, acc[d4 * 4 + 1]);
          acc[d4 * 4 + 2] = fmaf(p, vv.z, acc[d4 * 4 + 2]);
          acc[d4 * 4 + 3] = fmaf(p, vv.w, acc[d4 * 4 + 3]);
        }
      }
    }
    __syncthreads();
  }
  float inv = 1.0f / lrun;
  float* op = ctx + ((size_t)(b * TDEC + tid) * 256 + h * 32);
#pragma unroll
  for (int i = 0; i < 8; ++i) {
    ((float4*)op)[i] = make_float4(acc[i * 4 + 0] * inv, acc[i * 4 + 1] * inv,
                                   acc[i * 4 + 2] * inv, acc[i * 4 + 3] * inv);
  }
}

// ---------------- final: LN(dec_seq + ctxo) @ W_out + b_out ----------------
__global__ __launch_bounds__(256)
void k_final(const float* __restrict__ dec_seq, const float* __restrict__ ctxo,
             const float* __restrict__ g, const float* __restrict__ bb,
             const float* __restrict__ Wout, const float* __restrict__ bout,
             float* __restrict__ out) {
  const int wv = threadIdx.x >> 6, lane = threadIdx.x & 63;
  const int row = blockIdx.x * 4 + wv;
  const size_t base = (size_t)row * 256 + lane * 4;
  float4 dv = *(const float4*)(dec_seq + base);
  float4 cv = *(const float4*)(ctxo + base);
  float v[4] = {dv.x + cv.x, dv.y + cv.y, dv.z + cv.z, dv.w + cv.w};
  float s = v[0] + v[1] + v[2] + v[3];
#pragma unroll
  for (int off = 32; off >= 1; off >>= 1) s += __shfl_xor(s, off, 64);
  float m = s * (1.0f / 256.0f);
  float d2 = 0.f;
#pragma unroll
  for (int i = 0; i < 4; ++i) { float d = v[i] - m; d2 += d * d; }
#pragma unroll
  for (int off = 32; off >= 1; off >>= 1) d2 += __shfl_xor(d2, off, 64);
  float rs = rsqrtf(d2 * (1.0f / 256.0f) + LNEPS);
  float4 g4 = *(const float4*)(g + lane * 4);
  float4 b4 = *(const float4*)(bb + lane * 4);
  float4 w4 = *(const float4*)(Wout + lane * 4);
  float mix0 = g4.x * (v[0] - m) * rs + b4.x;
  float mix1 = g4.y * (v[1] - m) * rs + b4.y;
  float mix2 = g4.z * (v[2] - m) * rs + b4.z;
  float mix3 = g4.w * (v[3] - m) * rs + b4.w;
  float p = mix0 * w4.x + mix1 * w4.y + mix2 * w4.z + mix3 * w4.w;
#pragma unroll
  for (int off = 32; off >= 1; off >>= 1) p += __shfl_xor(p, off, 64);
  if (lane == 0) out[row] = p + bout[0];
}

extern "C" void kernel_launch(void* const* d_in, const int* in_sizes, int n_in,
                              void* d_out, int out_size, void* d_ws, size_t ws_size,
                              hipStream_t stream) {
  const float* enc_in   = (const float*)d_in[0];
  const float* dec_in   = (const float*)d_in[1];
  const float* ln_enc_g = (const float*)d_in[2];
  const float* ln_enc_b = (const float*)d_in[3];
  const float* W_enc    = (const float*)d_in[4];
  const float* U_enc    = (const float*)d_in[5];
  const float* b_enc    = (const float*)d_in[6];
  const float* W_dec    = (const float*)d_in[7];
  const float* U_dec    = (const float*)d_in[8];
  const float* b_dec    = (const float*)d_in[9];
  const float* Wq = (const float*)d_in[10]; const float* bq = (const float*)d_in[11];
  const float* Wk = (const float*)d_in[12]; const float* bk = (const float*)d_in[13];
  const float* Wv = (const float*)d_in[14]; const float* bv = (const float*)d_in[15];
  const float* Wo = (const float*)d_in[16]; const float* bo = (const float*)d_in[17];
  const float* ln_post_g = (const float*)d_in[18];
  const float* ln_post_b = (const float*)d_in[19];
  const float* W_out     = (const float*)d_in[20];
  const float* b_out     = (const float*)d_in[21];

  char* ws = (char*)d_ws;
  size_t off = 0;
  auto alloc = [&](size_t bytes) -> void* {
    void* p = ws + off;
    off += (bytes + 255) & ~(size_t)255;
    return p;
  };
  float* xln     = (float*)alloc((size_t)NBATCH * TENC * 8 * 4);
  u32*   upkE    = (u32*)  alloc((size_t)KP_TOT * GDIM * 4);
  u32*   upkD    = (u32*)  alloc((size_t)KP_TOT * GDIM * 4);
  float* enc_seq = (float*)alloc((size_t)NBATCH * TENC * 256 * 4);
  float* dec_seq = (float*)alloc((size_t)NBATCH * TDEC * 256 * 4);
  float* hfin    = (float*)alloc((size_t)NBATCH * 256 * 4);
  float* cfin    = (float*)alloc((size_t)NBATCH * 256 * 4);
  float* Qp      = (float*)alloc((size_t)NBATCH * NHEAD * TDEC * 32 * 4);
  u16*   Kb      = (u16*)  alloc((size_t)NBATCH * NHEAD * TENC * 32 * 2);
  u16*   Vb      = (u16*)  alloc((size_t)NBATCH * NHEAD * TENC * 32 * 2);
  float* ctx     = (float*)alloc((size_t)NBATCH * TDEC * 256 * 4);
  float* ctxo    = (float*)alloc((size_t)NBATCH * TDEC * 256 * 4);

  // 1. LN on encoder input
  k_ln8<<<dim3(256), dim3(256), 0, stream>>>(enc_in, ln_enc_g, ln_enc_b, xln,
                                             NBATCH * TENC);
  // 2. pack [U;W] to f16 pairs
  k_packUW<<<dim3((KP_TOT * GDIM + 255) / 256), dim3(256), 0, stream>>>(U_enc, W_enc, upkE);
  k_packUW<<<dim3((KP_TOT * GDIM + 255) / 256), dim3(256), 0, stream>>>(U_dec, W_dec, upkD);
  // 3. encoder scan
  k_scan2<<<dim3(NBATCH), dim3(1024), 0, stream>>>(
      xln, upkE, b_enc, nullptr, nullptr, enc_seq, hfin, cfin, TENC);
  // 4. decoder scan
  k_scan2<<<dim3(NBATCH), dim3(1024), 0, stream>>>(
      dec_in, upkD, b_dec, hfin, cfin, dec_seq, nullptr, nullptr, TDEC);
  // 5. projections
  k_gemm256<1><<<dim3(256, 4), dim3(256), 0, stream>>>(dec_seq, Wq, bq, Qp, NBATCH * TDEC, TDEC);
  k_gemm256<2><<<dim3(1024, 4), dim3(256), 0, stream>>>(enc_seq, Wk, bk, Kb, NBATCH * TENC, TENC);
  k_gemm256<2><<<dim3(1024, 4), dim3(256), 0, stream>>>(enc_seq, Wv, bv, Vb, NBATCH * TENC, TENC);
  // 6. attention
  k_attn<<<dim3(NBATCH * NHEAD), dim3(256), 0, stream>>>(Qp, Kb, Vb, ctx);
  // 7. output projection
  k_gemm256<0><<<dim3(256, 4), dim3(256), 0, stream>>>(ctx, Wo, bo, ctxo, NBATCH * TDEC, 0x7fffffff);
  // 8. residual + LN + final dot
  k_final<<<dim3(NBATCH * TDEC / 4), dim3(256), 0, stream>>>(
      dec_seq, ctxo, ln_post_g, ln_post_b, W_out, b_out, (float*)d_out);
}

// Round 3
// 3356.637 us; speedup vs baseline: 2.3544x; 1.0279x over previous
//
#include <hip/hip_runtime.h>
#include <stdint.h>

#define NBATCH 64
#define TENC   1024
#define TDEC   256
#define FDIM   8
#define UDIM   256
#define GDIM   1024
#define NHEAD  8
#define DHEAD  32
#define LNEPS  1e-5f

// ext-k = 256 (U rows) + 8 (W rows) = 264 rows -> 132 f16-pairs.
// 4 k-slices x 33 pairs. Per thread: 33 uint4 (pair x 4 gate cols);
// 24 in VGPR, 9 in LDS.
#define KP_W   33
#define KP_V   24
#define KP_L   9

typedef unsigned int   u32;
typedef unsigned short u16;

typedef _Float16 half2v __attribute__((ext_vector_type(2)));

__device__ __forceinline__ float bf2f_lo(u32 w) { return __uint_as_float(w << 16); }
__device__ __forceinline__ float bf2f_hi(u32 w) { return __uint_as_float(w & 0xFFFF0000u); }
__device__ __forceinline__ u16 f2bf(float f) {
  u32 u = __float_as_uint(f);
  u = (u + 0x7FFFu + ((u >> 16) & 1u)) >> 16;
  return (u16)u;
}
__device__ __forceinline__ u16 f2h_bits(float f) {
  _Float16 h = (_Float16)f;
  return __builtin_bit_cast(u16, h);
}
__device__ __forceinline__ float fdot2p(u32 wp, u32 hp, float acc) {
  return __builtin_amdgcn_fdot2(__builtin_bit_cast(half2v, wp),
                                __builtin_bit_cast(half2v, hp), acc, false);
}
__device__ __forceinline__ float sigf(float x) { return 1.0f / (1.0f + __expf(-x)); }
__device__ __forceinline__ float tanhf_fast(float x) {
  float ax = fabsf(x);
  float e  = __expf(2.0f * ax);
  float r  = 1.0f - 2.0f / (e + 1.0f);
  return copysignf(r, x);
}

// ---------------- LayerNorm over F=8 (encoder input) ----------------
__global__ __launch_bounds__(256)
void k_ln8(const float* __restrict__ x, const float* __restrict__ g,
           const float* __restrict__ bt, float* __restrict__ y, int rows) {
  int r = blockIdx.x * blockDim.x + threadIdx.x;
  if (r >= rows) return;
  const float* xp = x + (size_t)r * 8;
  float4 a = ((const float4*)xp)[0];
  float4 b4 = ((const float4*)xp)[1];
  float v[8] = {a.x, a.y, a.z, a.w, b4.x, b4.y, b4.z, b4.w};
  float m = 0.f;
#pragma unroll
  for (int i = 0; i < 8; ++i) m += v[i];
  m *= 0.125f;
  float var = 0.f;
#pragma unroll
  for (int i = 0; i < 8; ++i) { float d = v[i] - m; var += d * d; }
  var *= 0.125f;
  float rs = rsqrtf(var + LNEPS);
  float o[8];
#pragma unroll
  for (int i = 0; i < 8; ++i) o[i] = g[i] * (v[i] - m) * rs + bt[i];
  float* yp = y + (size_t)r * 8;
  ((float4*)yp)[0] = make_float4(o[0], o[1], o[2], o[3]);
  ((float4*)yp)[1] = make_float4(o[4], o[5], o[6], o[7]);
}

// ---- pack weights: out[gp*256 + u] = uint4 over gates g=0..3 of
//      f16pair(rows 2gp,2gp+1 ; col g*256+u). Rows 0..255 = U, 256..263 = W.
__global__ __launch_bounds__(256)
void k_packUW2(const float* __restrict__ U, const float* __restrict__ W,
               uint4* __restrict__ out) {
  int idx = blockIdx.x * 256 + threadIdx.x;  // 132*256
  int gp = idx >> 8, u = idx & 255;
  int r0 = 2 * gp, r1 = 2 * gp + 1;
  const float* R0 = (r0 < 256) ? (U + (size_t)r0 * GDIM) : (W + (size_t)(r0 - 256) * GDIM);
  const float* R1 = (r1 < 256) ? (U + (size_t)r1 * GDIM) : (W + (size_t)(r1 - 256) * GDIM);
  uint4 o;
  u32* oc = (u32*)&o;
#pragma unroll
  for (int g = 0; g < 4; ++g) {
    int c = g * 256 + u;
    oc[g] = (u32)f2h_bits(R0[c]) | ((u32)f2h_bits(R1[c]) << 16);
  }
  out[idx] = o;
}

// ---------------- LSTM scan v3 ----------------
// 64 blocks x 1024 threads. Wave w: ks=w>>2 (k-slice), cg=w&3.
// Thread owns unit u = cg*64+lane -> gate cols {u,256+u,512+u,768+u}.
// Waves 0-3 (ks=0, tid<256, u==tid) are also the gate waves.
#define DOT4(w4, hh)                                              \
  do {                                                            \
    a0 = fdot2p((w4).x, (hh), a0); a1 = fdot2p((w4).y, (hh), a1); \
    a2 = fdot2p((w4).z, (hh), a2); a3 = fdot2p((w4).w, (hh), a3); \
  } while (0)

__global__ __launch_bounds__(1024, 4)
void k_scan3(const float* __restrict__ xseq,  // [B,T,8]
             const uint4* __restrict__ Wpk,   // [132*256] uint4
             const float* __restrict__ bias,  // [1024]
             const float* __restrict__ h0, const float* __restrict__ c0,
             float* __restrict__ seq_out,     // [B,T,256]
             float* __restrict__ hT, float* __restrict__ cT, int T) {
  __shared__ __align__(16) uint4  wl[1024 * KP_L];  // 144 KB
  __shared__ __align__(16) float4 zp[3 * 256];      // 12 KB k-partials (slices 1..3)
  __shared__ __align__(16) u32    hpk[4 * 36];      // 576 B: 4 slices x 33 pairs (pad 36)

  const int tid = threadIdx.x, b = blockIdx.x;
  const int w = tid >> 6, lane = tid & 63;
  const int ks = w >> 2, cg = w & 3;
  const int u = cg * 64 + lane;

  // ---- load weights ----
  const int base = ks * KP_W * 256 + u;
  uint4 wv[KP_V];
#pragma unroll
  for (int i = 0; i < KP_V; ++i) wv[i] = Wpk[base + i * 256];
  const int widx = tid * KP_L;
#pragma unroll
  for (int i = 0; i < KP_L; ++i) wl[widx + i] = Wpk[base + (KP_V + i) * 256];

  // ---- gate-thread constants (valid for tid<256) ----
  const float bi = bias[u], bf = bias[256 + u], bg = bias[512 + u], bo = bias[768 + u];
  // u16 slot in hpk for h-unit u: global pair m=u>>1, slice s, padded idx
  const int m_ = u >> 1;
  const int s_ = (m_ >= 99) ? 3 : (m_ >= 66) ? 2 : (m_ >= 33) ? 1 : 0;
  const int hoff = (s_ * 36 + (m_ - s_ * 33)) * 2 + (u & 1);

  // x-stager identity: wave 15 lanes 0..7 (tid 960..967)
  const bool is_x = (tid >= 960 && tid < 968);
  const int xj = tid - 960;
  const int xoff = (3 * 36 + 29 + (xj >> 1)) * 2 + (xj & 1);

  // ---- init state ----
  float c_reg = 0.f, h_last = 0.f;
  if (tid < 256) {
    float hv = h0 ? h0[b * 256 + u] : 0.f;
    c_reg = c0 ? c0[b * 256 + u] : 0.f;
    h_last = hv;
    ((u16*)hpk)[hoff] = f2h_bits(hv);
  }
  if (is_x) {
    float xv = xseq[(size_t)(b * T + 0) * 8 + xj];
    ((u16*)hpk)[xoff] = f2h_bits(xv);
  }
  __syncthreads();

  const u32* hrow = hpk + ks * 36;
  for (int t = 0; t < T; ++t) {
    float xv_next = 0.f;
    if (is_x) {
      int t2 = (t + 1 < T) ? (t + 1) : (T - 1);
      xv_next = xseq[(size_t)(b * T + t2) * 8 + xj];  // overlaps with dots
    }
    // ---- dot phase ----
    float a0 = 0.f, a1 = 0.f, a2 = 0.f, a3 = 0.f;
#pragma unroll
    for (int ch = 0; ch < 6; ++ch) {  // pairs 0..23 (VGPR)
      uint4 hq = *(const uint4*)(hrow + ch * 4);
      DOT4(wv[ch * 4 + 0], hq.x);
      DOT4(wv[ch * 4 + 1], hq.y);
      DOT4(wv[ch * 4 + 2], hq.z);
      DOT4(wv[ch * 4 + 3], hq.w);
    }
    {  // pairs 24..32 (LDS)
      uint4 hq6 = *(const uint4*)(hrow + 24);
      uint4 hq7 = *(const uint4*)(hrow + 28);
      u32 h32 = hrow[32];
      uint4 w4;
      w4 = wl[widx + 0]; DOT4(w4, hq6.x);
      w4 = wl[widx + 1]; DOT4(w4, hq6.y);
      w4 = wl[widx + 2]; DOT4(w4, hq6.z);
      w4 = wl[widx + 3]; DOT4(w4, hq6.w);
      w4 = wl[widx + 4]; DOT4(w4, hq7.x);
      w4 = wl[widx + 5]; DOT4(w4, hq7.y);
      w4 = wl[widx + 6]; DOT4(w4, hq7.z);
      w4 = wl[widx + 7]; DOT4(w4, hq7.w);
      w4 = wl[widx + 8]; DOT4(w4, h32);
    }
    if (ks) zp[(ks - 1) * 256 + u] = make_float4(a0, a1, a2, a3);
    __syncthreads();

    // ---- gate phase (waves 0-3) ----
    if (tid < 256) {
      float4 p1 = zp[u], p2 = zp[256 + u], p3 = zp[512 + u];
      float zi = a0 + bi + p1.x + p2.x + p3.x;
      float zf = a1 + bf + p1.y + p2.y + p3.y;
      float zg = a2 + bg + p1.z + p2.z + p3.z;
      float zo = a3 + bo + p1.w + p2.w + p3.w;
      float ig = sigf(zi), fg = sigf(zf);
      float gg = tanhf_fast(zg), og = sigf(zo);
      c_reg = fg * c_reg + ig * gg;
      float h = og * tanhf_fast(c_reg);
      h_last = h;
      seq_out[(size_t)(b * T + t) * 256 + u] = h;
      ((u16*)hpk)[hoff] = f2h_bits(h);
    }
    if (is_x) ((u16*)hpk)[xoff] = f2h_bits(xv_next);
    __syncthreads();
  }
  if (hT && tid < 256) {
    hT[b * 256 + u] = h_last;
    cT[b * 256 + u] = c_reg;
  }
}

// ---------------- GEMM: C[M,256] = A[M,256] @ B[256,256] + bias ----------------
template <int OMODE>
__global__ __launch_bounds__(256)
void k_gemm256(const float* __restrict__ A, const float* __restrict__ Bw,
               const float* __restrict__ bias, void* __restrict__ outp,
               int M, int Tdim) {
  __shared__ __align__(16) float As[16][68];
  __shared__ __align__(16) float Bs[16][68];
  const int tid = threadIdx.x;
  const int tx = tid & 15, ty = tid >> 4;
  const int bm = blockIdx.x * 64, bn = blockIdx.y * 64;
  const int ar = tid >> 2, ac = (tid & 3) << 2;
  const int br = tid >> 4, bc = (tid & 15) << 2;
  float acc[4][4] = {};
  for (int k0 = 0; k0 < 256; k0 += 16) {
    float4 av = *(const float4*)(A + (size_t)(bm + ar) * 256 + k0 + ac);
    As[ac + 0][ar] = av.x; As[ac + 1][ar] = av.y;
    As[ac + 2][ar] = av.z; As[ac + 3][ar] = av.w;
    float4 bv = *(const float4*)(Bw + (size_t)(k0 + br) * 256 + bn + bc);
    *(float4*)&Bs[br][bc] = bv;
    __syncthreads();
#pragma unroll
    for (int k = 0; k < 16; ++k) {
      float4 a4 = *(const float4*)&As[k][ty << 2];
      float4 b4 = *(const float4*)&Bs[k][tx << 2];
      float aa[4] = {a4.x, a4.y, a4.z, a4.w};
      float bb[4] = {b4.x, b4.y, b4.z, b4.w};
#pragma unroll
      for (int i = 0; i < 4; ++i)
#pragma unroll
        for (int jj = 0; jj < 4; ++jj)
          acc[i][jj] = fmaf(aa[i], bb[jj], acc[i][jj]);
    }
    __syncthreads();
  }
#pragma unroll
  for (int i = 0; i < 4; ++i) {
    int mm = bm + (ty << 2) + i;
#pragma unroll
    for (int jj = 0; jj < 4; ++jj) {
      int n = bn + (tx << 2) + jj;
      float v = acc[i][jj] + bias[n];
      if (OMODE == 0) {
        ((float*)outp)[(size_t)mm * 256 + n] = v;
      } else {
        int bb_ = mm / Tdim, t = mm % Tdim;
        int hh = n >> 5, dd = n & 31;
        size_t o = ((((size_t)bb_ * NHEAD + hh) * Tdim) + t) * 32 + dd;
        if (OMODE == 1) ((float*)outp)[o] = v;
        else            ((u16*)outp)[o]   = f2bf(v);
      }
    }
  }
}

// ---------------- attention: one block per (b,h); thread = q row ----------------
__global__ __launch_bounds__(256)
void k_attn(const float* __restrict__ Q, const u16* __restrict__ Kb,
            const u16* __restrict__ Vb, float* __restrict__ ctx) {
  const int bh = blockIdx.x;
  const int b = bh >> 3, h = bh & 7;
  const int tid = threadIdx.x;
  __shared__ __align__(16) float Kl[64][36];
  __shared__ __align__(16) float Vl[64][36];
  float q[32];
  {
    const float* qp = Q + ((size_t)bh * TDEC + tid) * 32;
#pragma unroll
    for (int i = 0; i < 8; ++i) {
      float4 v = ((const float4*)qp)[i];
      q[i * 4 + 0] = v.x * 0.17677669529663687f;
      q[i * 4 + 1] = v.y * 0.17677669529663687f;
      q[i * 4 + 2] = v.z * 0.17677669529663687f;
      q[i * 4 + 3] = v.w * 0.17677669529663687f;
    }
  }
  float mrun = -3.0e38f, lrun = 0.f;
  float acc[32];
#pragma unroll
  for (int i = 0; i < 32; ++i) acc[i] = 0.f;
  const int lr = tid >> 2, lc = (tid & 3) << 3;
  for (int kt = 0; kt < TENC; kt += 64) {
    {
      uint4 kw = *(const uint4*)(Kb + ((size_t)bh * TENC + kt + lr) * 32 + lc);
      Kl[lr][lc + 0] = bf2f_lo(kw.x); Kl[lr][lc + 1] = bf2f_hi(kw.x);
      Kl[lr][lc + 2] = bf2f_lo(kw.y); Kl[lr][lc + 3] = bf2f_hi(kw.y);
      Kl[lr][lc + 4] = bf2f_lo(kw.z); Kl[lr][lc + 5] = bf2f_hi(kw.z);
      Kl[lr][lc + 6] = bf2f_lo(kw.w); Kl[lr][lc + 7] = bf2f_hi(kw.w);
      uint4 vw = *(const uint4*)(Vb + ((size_t)bh * TENC + kt + lr) * 32 + lc);
      Vl[lr][lc + 0] = bf2f_lo(vw.x); Vl[lr][lc + 1] = bf2f_hi(vw.x);
      Vl[lr][lc + 2] = bf2f_lo(vw.y); Vl[lr][lc + 3] = bf2f_hi(vw.y);
      Vl[lr][lc + 4] = bf2f_lo(vw.z); Vl[lr][lc + 5] = bf2f_hi(vw.z);
      Vl[lr][lc + 6] = bf2f_lo(vw.w); Vl[lr][lc + 7] = bf2f_hi(vw.w);
    }
    __syncthreads();
#pragma unroll
    for (int cch = 0; cch < 8; ++cch) {
      float s8[8];
#pragma unroll
      for (int i = 0; i < 8; ++i) {
        const float4* kr = (const float4*)&Kl[cch * 8 + i][0];
        float ss = 0.f;
#pragma unroll
        for (int d4 = 0; d4 < 8; ++d4) {
          float4 kv = kr[d4];
          ss = fmaf(q[d4 * 4 + 0], kv.x, ss);
          ss = fmaf(q[d4 * 4 + 1], kv.y, ss);
          ss = fmaf(q[d4 * 4 + 2], kv.z, ss);
          ss = fmaf(q[d4 * 4 + 3], kv.w, ss);
        }
        s8[i] = ss;
      }
      float mnew = mrun;
#pragma unroll
      for (int i = 0; i < 8; ++i) mnew = fmaxf(mnew, s8[i]);
      float sc = __expf(mrun - mnew);
      mrun = mnew;
      lrun *= sc;
#pragma unroll
      for (int d = 0; d < 32; ++d) acc[d] *= sc;
#pragma unroll
      for (int i = 0; i < 8; ++i) {
        float p = __expf(s8[i] - mnew);
        lrun += p;
        const float4* vr = (const float4*)&Vl[cch * 8 + i][0];
#pragma unroll
        for (int d4 = 0; d4 < 8; ++d4) {
          float4 vv = vr[d4];
          acc[d4 * 4 + 0] = fmaf(p, vv.x, acc[d4 * 4 + 0]);
          acc[d4 * 4 + 1] = fmaf(p, vv.y, acc[d4 * 4 + 1]);
          acc[d4 * 4 + 2] = fmaf(p, vv.z, acc[d4 * 4 + 2]);
          acc[d4 * 4 + 3] = fmaf(p, vv.w, acc[d4 * 4 + 3]);
        }
      }
    }
    __syncthreads();
  }
  float inv = 1.0f / lrun;
  float* op = ctx + ((size_t)(b * TDEC + tid) * 256 + h * 32);
#pragma unroll
  for (int i = 0; i < 8; ++i) {
    ((float4*)op)[i] = make_float4(acc[i * 4 + 0] * inv, acc[i * 4 + 1] * inv,
                                   acc[i * 4 + 2] * inv, acc[i * 4 + 3] * inv);
  }
}

// ---------------- final: LN(dec_seq + ctxo) @ W_out + b_out ----------------
__global__ __launch_bounds__(256)
void k_final(const float* __restrict__ dec_seq, const float* __restrict__ ctxo,
             const float* __restrict__ g, const float* __restrict__ bb,
             const float* __restrict__ Wout, const float* __restrict__ bout,
             float* __restrict__ out) {
  const int wv = threadIdx.x >> 6, lane = threadIdx.x & 63;
  const int row = blockIdx.x * 4 + wv;
  const size_t base = (size_t)row * 256 + lane * 4;
  float4 dv = *(const float4*)(dec_seq + base);
  float4 cv = *(const float4*)(ctxo + base);
  float v[4] = {dv.x + cv.x, dv.y + cv.y, dv.z + cv.z, dv.w + cv.w};
  float s = v[0] + v[1] + v[2] + v[3];
#pragma unroll
  for (int off = 32; off >= 1; off >>= 1) s += __shfl_xor(s, off, 64);
  float m = s * (1.0f / 256.0f);
  float d2 = 0.f;
#pragma unroll
  for (int i = 0; i < 4; ++i) { float d = v[i] - m; d2 += d * d; }
#pragma unroll
  for (int off = 32; off >= 1; off >>= 1) d2 += __shfl_xor(d2, off, 64);
  float rs = rsqrtf(d2 * (1.0f / 256.0f) + LNEPS);
  float4 g4 = *(const float4*)(g + lane * 4);
  float4 b4 = *(const float4*)(bb + lane * 4);
  float4 w4 = *(const float4*)(Wout + lane * 4);
  float mix0 = g4.x * (v[0] - m) * rs + b4.x;
  float mix1 = g4.y * (v[1] - m) * rs + b4.y;
  float mix2 = g4.z * (v[2] - m) * rs + b4.z;
  float mix3 = g4.w * (v[3] - m) * rs + b4.w;
  float p = mix0 * w4.x + mix1 * w4.y + mix2 * w4.z + mix3 * w4.w;
#pragma unroll
  for (int off = 32; off >= 1; off >>= 1) p += __shfl_xor(p, off, 64);
  if (lane == 0) out[row] = p + bout[0];
}

extern "C" void kernel_launch(void* const* d_in, const int* in_sizes, int n_in,
                              void* d_out, int out_size, void* d_ws, size_t ws_size,
                              hipStream_t stream) {
  const float* enc_in   = (const float*)d_in[0];
  const float* dec_in   = (const float*)d_in[1];
  const float* ln_enc_g = (const float*)d_in[2];
  const float* ln_enc_b = (const float*)d_in[3];
  const float* W_enc    = (const float*)d_in[4];
  const float* U_enc    = (const float*)d_in[5];
  const float* b_enc    = (const float*)d_in[6];
  const float* W_dec    = (const float*)d_in[7];
  const float* U_dec    = (const float*)d_in[8];
  const float* b_dec    = (const float*)d_in[9];
  const float* Wq = (const float*)d_in[10]; const float* bq = (const float*)d_in[11];
  const float* Wk = (const float*)d_in[12]; const float* bk = (const float*)d_in[13];
  const float* Wv = (const float*)d_in[14]; const float* bv = (const float*)d_in[15];
  const float* Wo = (const float*)d_in[16]; const float* bo = (const float*)d_in[17];
  const float* ln_post_g = (const float*)d_in[18];
  const float* ln_post_b = (const float*)d_in[19];
  const float* W_out     = (const float*)d_in[20];
  const float* b_out     = (const float*)d_in[21];

  char* ws = (char*)d_ws;
  size_t off = 0;
  auto alloc = [&](size_t bytes) -> void* {
    void* p = ws + off;
    off += (bytes + 255) & ~(size_t)255;
    return p;
  };
  float* xln     = (float*)alloc((size_t)NBATCH * TENC * 8 * 4);
  uint4* upkE    = (uint4*)alloc((size_t)132 * 256 * 16);
  uint4* upkD    = (uint4*)alloc((size_t)132 * 256 * 16);
  float* enc_seq = (float*)alloc((size_t)NBATCH * TENC * 256 * 4);
  float* dec_seq = (float*)alloc((size_t)NBATCH * TDEC * 256 * 4);
  float* hfin    = (float*)alloc((size_t)NBATCH * 256 * 4);
  float* cfin    = (float*)alloc((size_t)NBATCH * 256 * 4);
  float* Qp      = (float*)alloc((size_t)NBATCH * NHEAD * TDEC * 32 * 4);
  u16*   Kb      = (u16*)  alloc((size_t)NBATCH * NHEAD * TENC * 32 * 2);
  u16*   Vb      = (u16*)  alloc((size_t)NBATCH * NHEAD * TENC * 32 * 2);
  float* ctx     = (float*)alloc((size_t)NBATCH * TDEC * 256 * 4);
  float* ctxo    = (float*)alloc((size_t)NBATCH * TDEC * 256 * 4);

  // 1. LN on encoder input
  k_ln8<<<dim3(256), dim3(256), 0, stream>>>(enc_in, ln_enc_g, ln_enc_b, xln,
                                             NBATCH * TENC);
  // 2. pack [U;W] -> per-unit gate-quad f16 pairs
  k_packUW2<<<dim3(132), dim3(256), 0, stream>>>(U_enc, W_enc, upkE);
  k_packUW2<<<dim3(132), dim3(256), 0, stream>>>(U_dec, W_dec, upkD);
  // 3. encoder scan
  k_scan3<<<dim3(NBATCH), dim3(1024), 0, stream>>>(
      xln, upkE, b_enc, nullptr, nullptr, enc_seq, hfin, cfin, TENC);
  // 4. decoder scan
  k_scan3<<<dim3(NBATCH), dim3(1024), 0, stream>>>(
      dec_in, upkD, b_dec, hfin, cfin, dec_seq, nullptr, nullptr, TDEC);
  // 5. projections
  k_gemm256<1><<<dim3(256, 4), dim3(256), 0, stream>>>(dec_seq, Wq, bq, Qp, NBATCH * TDEC, TDEC);
  k_gemm256<2><<<dim3(1024, 4), dim3(256), 0, stream>>>(enc_seq, Wk, bk, Kb, NBATCH * TENC, TENC);
  k_gemm256<2><<<dim3(1024, 4), dim3(256), 0, stream>>>(enc_seq, Wv, bv, Vb, NBATCH * TENC, TENC);
  // 6. attention
  k_attn<<<dim3(NBATCH * NHEAD), dim3(256), 0, stream>>>(Qp, Kb, Vb, ctx);
  // 7. output projection
  k_gemm256<0><<<dim3(256, 4), dim3(256), 0, stream>>>(ctx, Wo, bo, ctxo, NBATCH * TDEC, 0x7fffffff);
  // 8. residual + LN + final dot
  k_final<<<dim3(NBATCH * TDEC / 4), dim3(256), 0, stream>>>(
      dec_seq, ctxo, ln_post_g, ln_post_b, W_out, b_out, (float*)d_out);
}

// Round 4
// 3268.465 us; speedup vs baseline: 2.4179x; 1.0270x over previous
//
#include <hip/hip_runtime.h>
#include <stdint.h>

#define NBATCH 64
#define TENC   1024
#define TDEC   256
#define FDIM   8
#define UDIM   256
#define GDIM   1024
#define NHEAD  8
#define DHEAD  32
#define LNEPS  1e-5f

// ext-k = 256 (U rows) + 8 (W rows) = 264 rows -> 132 f16-pairs.
// 4 k-slices x 33 pairs. Per thread: 33 uint4 (pair x 4 gate cols);
// 24 pinned in VGPR, 9 in LDS.
#define KP_W   33
#define KP_V   24
#define KP_L   9

typedef unsigned int   u32;
typedef unsigned short u16;

typedef _Float16 half2v __attribute__((ext_vector_type(2)));

__device__ __forceinline__ float bf2f_lo(u32 w) { return __uint_as_float(w << 16); }
__device__ __forceinline__ float bf2f_hi(u32 w) { return __uint_as_float(w & 0xFFFF0000u); }
__device__ __forceinline__ u16 f2bf(float f) {
  u32 u = __float_as_uint(f);
  u = (u + 0x7FFFu + ((u >> 16) & 1u)) >> 16;
  return (u16)u;
}
__device__ __forceinline__ u16 f2h_bits(float f) {
  _Float16 h = (_Float16)f;
  return __builtin_bit_cast(u16, h);
}
__device__ __forceinline__ float fdot2p(u32 wp, u32 hp, float acc) {
  return __builtin_amdgcn_fdot2(__builtin_bit_cast(half2v, wp),
                                __builtin_bit_cast(half2v, hp), acc, false);
}
__device__ __forceinline__ float sigf(float x) { return 1.0f / (1.0f + __expf(-x)); }
__device__ __forceinline__ float tanhf_fast(float x) {
  float ax = fabsf(x);
  float e  = __expf(2.0f * ax);
  float r  = 1.0f - 2.0f / (e + 1.0f);
  return copysignf(r, x);
}

// ---------------- LayerNorm over F=8 (encoder input) ----------------
__global__ __launch_bounds__(256)
void k_ln8(const float* __restrict__ x, const float* __restrict__ g,
           const float* __restrict__ bt, float* __restrict__ y, int rows) {
  int r = blockIdx.x * blockDim.x + threadIdx.x;
  if (r >= rows) return;
  const float* xp = x + (size_t)r * 8;
  float4 a = ((const float4*)xp)[0];
  float4 b4 = ((const float4*)xp)[1];
  float v[8] = {a.x, a.y, a.z, a.w, b4.x, b4.y, b4.z, b4.w};
  float m = 0.f;
#pragma unroll
  for (int i = 0; i < 8; ++i) m += v[i];
  m *= 0.125f;
  float var = 0.f;
#pragma unroll
  for (int i = 0; i < 8; ++i) { float d = v[i] - m; var += d * d; }
  var *= 0.125f;
  float rs = rsqrtf(var + LNEPS);
  float o[8];
#pragma unroll
  for (int i = 0; i < 8; ++i) o[i] = g[i] * (v[i] - m) * rs + bt[i];
  float* yp = y + (size_t)r * 8;
  ((float4*)yp)[0] = make_float4(o[0], o[1], o[2], o[3]);
  ((float4*)yp)[1] = make_float4(o[4], o[5], o[6], o[7]);
}

// ---- pack weights: out[gp*256 + u] = uint4 over gates g=0..3 of
//      f16pair(rows 2gp,2gp+1 ; col g*256+u). Rows 0..255 = U, 256..263 = W.
__global__ __launch_bounds__(256)
void k_packUW2(const float* __restrict__ U, const float* __restrict__ W,
               uint4* __restrict__ out) {
  int idx = blockIdx.x * 256 + threadIdx.x;  // 132*256
  int gp = idx >> 8, u = idx & 255;
  int r0 = 2 * gp, r1 = 2 * gp + 1;
  const float* R0 = (r0 < 256) ? (U + (size_t)r0 * GDIM) : (W + (size_t)(r0 - 256) * GDIM);
  const float* R1 = (r1 < 256) ? (U + (size_t)r1 * GDIM) : (W + (size_t)(r1 - 256) * GDIM);
  uint4 o;
  u32* oc = (u32*)&o;
#pragma unroll
  for (int g = 0; g < 4; ++g) {
    int c = g * 256 + u;
    oc[g] = (u32)f2h_bits(R0[c]) | ((u32)f2h_bits(R1[c]) << 16);
  }
  out[idx] = o;
}

// ---------------- LSTM scan v4: pinned-register weights ----------------
// 64 blocks x 1024 threads. Wave w: ks=w>>2 (k-slice), cg=w&3.
// Thread owns unit u = cg*64+lane -> gate cols {u,256+u,512+u,768+u}.
// Waves 0-3 (ks=0, tid<256, u==tid) are also the gate waves.
#define DOT4(w4, hh)                                              \
  do {                                                            \
    a0 = fdot2p((w4).x, (hh), a0); a1 = fdot2p((w4).y, (hh), a1); \
    a2 = fdot2p((w4).z, (hh), a2); a3 = fdot2p((w4).w, (hh), a3); \
  } while (0)

__global__ void __launch_bounds__(1024)
__attribute__((amdgpu_waves_per_eu(4, 4)))
k_scan4(const float* __restrict__ xseq,  // [B,T,8]
        const uint4* __restrict__ Wpk,   // [132*256] uint4
        const float* __restrict__ bias,  // [1024]
        const float* __restrict__ h0, const float* __restrict__ c0,
        float* __restrict__ seq_out,     // [B,T,256]
        float* __restrict__ hT, float* __restrict__ cT, int T) {
  __shared__ __align__(16) uint4  wl[1024 * KP_L];  // 144 KB
  __shared__ __align__(16) float4 zp[3 * 256];      // 12 KB k-partials (slices 1..3)
  __shared__ __align__(16) u32    hpk[4 * 36];      // 576 B: 4 slices x 33 pairs (pad 36)

  const int tid = threadIdx.x, b = blockIdx.x;
  const int w = tid >> 6, lane = tid & 63;
  const int ks = w >> 2, cg = w & 3;
  const int u = cg * 64 + lane;

  // ---- load weights: 24 uint4 pinned to VGPR (opaque asm kills remat), 9 -> LDS ----
  const int base = ks * KP_W * 256 + u;
  uint4 wv[KP_V];
#pragma unroll
  for (int i = 0; i < KP_V; ++i) {
    wv[i] = Wpk[base + i * 256];
    asm volatile("" : "+v"(wv[i].x), "+v"(wv[i].y), "+v"(wv[i].z), "+v"(wv[i].w));
  }
  const int widx = tid * KP_L;
#pragma unroll
  for (int i = 0; i < KP_L; ++i) wl[widx + i] = Wpk[base + (KP_V + i) * 256];

  // ---- gate-thread constants (valid for tid<256) ----
  const float bi = bias[u], bf = bias[256 + u], bg = bias[512 + u], bo = bias[768 + u];
  const int m_ = u >> 1;
  const int s_ = (m_ >= 99) ? 3 : (m_ >= 66) ? 2 : (m_ >= 33) ? 1 : 0;
  const int hoff = (s_ * 36 + (m_ - s_ * 33)) * 2 + (u & 1);

  // x-stager identity: wave 15 lanes 0..7 (tid 960..967)
  const bool is_x = (tid >= 960 && tid < 968);
  const int xj = tid - 960;
  const int xoff = (3 * 36 + 29 + (xj >> 1)) * 2 + (xj & 1);

  // ---- init state ----
  float c_reg = 0.f, h_last = 0.f;
  if (tid < 256) {
    float hv = h0 ? h0[b * 256 + u] : 0.f;
    c_reg = c0 ? c0[b * 256 + u] : 0.f;
    h_last = hv;
    ((u16*)hpk)[hoff] = f2h_bits(hv);
  }
  if (is_x) {
    float xv = xseq[(size_t)(b * T + 0) * 8 + xj];
    ((u16*)hpk)[xoff] = f2h_bits(xv);
  }
  __syncthreads();

  const u32* hrow = hpk + ks * 36;
  for (int t = 0; t < T; ++t) {
    float xv_next = 0.f;
    if (is_x) {
      int t2 = (t + 1 < T) ? (t + 1) : (T - 1);
      xv_next = xseq[(size_t)(b * T + t2) * 8 + xj];  // overlaps with dots
    }
    // ---- dot phase ----
    float a0 = 0.f, a1 = 0.f, a2 = 0.f, a3 = 0.f;
#pragma unroll
    for (int ch = 0; ch < 6; ++ch) {  // pairs 0..23 (VGPR)
      uint4 hq = *(const uint4*)(hrow + ch * 4);
      DOT4(wv[ch * 4 + 0], hq.x);
      DOT4(wv[ch * 4 + 1], hq.y);
      DOT4(wv[ch * 4 + 2], hq.z);
      DOT4(wv[ch * 4 + 3], hq.w);
    }
    {  // pairs 24..32 (LDS)
      uint4 hq6 = *(const uint4*)(hrow + 24);
      uint4 hq7 = *(const uint4*)(hrow + 28);
      u32 h32 = hrow[32];
      uint4 w4;
      w4 = wl[widx + 0]; DOT4(w4, hq6.x);
      w4 = wl[widx + 1]; DOT4(w4, hq6.y);
      w4 = wl[widx + 2]; DOT4(w4, hq6.z);
      w4 = wl[widx + 3]; DOT4(w4, hq6.w);
      w4 = wl[widx + 4]; DOT4(w4, hq7.x);
      w4 = wl[widx + 5]; DOT4(w4, hq7.y);
      w4 = wl[widx + 6]; DOT4(w4, hq7.z);
      w4 = wl[widx + 7]; DOT4(w4, hq7.w);
      w4 = wl[widx + 8]; DOT4(w4, h32);
    }
    if (ks) zp[(ks - 1) * 256 + u] = make_float4(a0, a1, a2, a3);
    __syncthreads();

    // ---- gate phase (waves 0-3) ----
    if (tid < 256) {
      float4 p1 = zp[u], p2 = zp[256 + u], p3 = zp[512 + u];
      float zi = a0 + bi + p1.x + p2.x + p3.x;
      float zf = a1 + bf + p1.y + p2.y + p3.y;
      float zg = a2 + bg + p1.z + p2.z + p3.z;
      float zo = a3 + bo + p1.w + p2.w + p3.w;
      float ig = sigf(zi), fg = sigf(zf);
      float gg = tanhf_fast(zg), og = sigf(zo);
      c_reg = fg * c_reg + ig * gg;
      float h = og * tanhf_fast(c_reg);
      h_last = h;
      seq_out[(size_t)(b * T + t) * 256 + u] = h;
      ((u16*)hpk)[hoff] = f2h_bits(h);
    }
    if (is_x) ((u16*)hpk)[xoff] = f2h_bits(xv_next);
    __syncthreads();
  }
  if (hT && tid < 256) {
    hT[b * 256 + u] = h_last;
    cT[b * 256 + u] = c_reg;
  }
}

// ---------------- GEMM: C[M,256] = A[M,256] @ B[256,256] + bias ----------------
template <int OMODE>
__global__ __launch_bounds__(256)
void k_gemm256(const float* __restrict__ A, const float* __restrict__ Bw,
               const float* __restrict__ bias, void* __restrict__ outp,
               int M, int Tdim) {
  __shared__ __align__(16) float As[16][68];
  __shared__ __align__(16) float Bs[16][68];
  const int tid = threadIdx.x;
  const int tx = tid & 15, ty = tid >> 4;
  const int bm = blockIdx.x * 64, bn = blockIdx.y * 64;
  const int ar = tid >> 2, ac = (tid & 3) << 2;
  const int br = tid >> 4, bc = (tid & 15) << 2;
  float acc[4][4] = {};
  for (int k0 = 0; k0 < 256; k0 += 16) {
    float4 av = *(const float4*)(A + (size_t)(bm + ar) * 256 + k0 + ac);
    As[ac + 0][ar] = av.x; As[ac + 1][ar] = av.y;
    As[ac + 2][ar] = av.z; As[ac + 3][ar] = av.w;
    float4 bv = *(const float4*)(Bw + (size_t)(k0 + br) * 256 + bn + bc);
    *(float4*)&Bs[br][bc] = bv;
    __syncthreads();
#pragma unroll
    for (int k = 0; k < 16; ++k) {
      float4 a4 = *(const float4*)&As[k][ty << 2];
      float4 b4 = *(const float4*)&Bs[k][tx << 2];
      float aa[4] = {a4.x, a4.y, a4.z, a4.w};
      float bb[4] = {b4.x, b4.y, b4.z, b4.w};
#pragma unroll
      for (int i = 0; i < 4; ++i)
#pragma unroll
        for (int jj = 0; jj < 4; ++jj)
          acc[i][jj] = fmaf(aa[i], bb[jj], acc[i][jj]);
    }
    __syncthreads();
  }
#pragma unroll
  for (int i = 0; i < 4; ++i) {
    int mm = bm + (ty << 2) + i;
#pragma unroll
    for (int jj = 0; jj < 4; ++jj) {
      int n = bn + (tx << 2) + jj;
      float v = acc[i][jj] + bias[n];
      if (OMODE == 0) {
        ((float*)outp)[(size_t)mm * 256 + n] = v;
      } else {
        int bb_ = mm / Tdim, t = mm % Tdim;
        int hh = n >> 5, dd = n & 31;
        size_t o = ((((size_t)bb_ * NHEAD + hh) * Tdim) + t) * 32 + dd;
        if (OMODE == 1) ((float*)outp)[o] = v;
        else            ((u16*)outp)[o]   = f2bf(v);
      }
    }
  }
}

// ---------------- attention: one block per (b,h); thread = q row ----------------
__global__ __launch_bounds__(256)
void k_attn(const float* __restrict__ Q, const u16* __restrict__ Kb,
            const u16* __restrict__ Vb, float* __restrict__ ctx) {
  const int bh = blockIdx.x;
  const int b = bh >> 3, h = bh & 7;
  const int tid = threadIdx.x;
  __shared__ __align__(16) float Kl[64][36];
  __shared__ __align__(16) float Vl[64][36];
  float q[32];
  {
    const float* qp = Q + ((size_t)bh * TDEC + tid) * 32;
#pragma unroll
    for (int i = 0; i < 8; ++i) {
      float4 v = ((const float4*)qp)[i];
      q[i * 4 + 0] = v.x * 0.17677669529663687f;
      q[i * 4 + 1] = v.y * 0.17677669529663687f;
      q[i * 4 + 2] = v.z * 0.17677669529663687f;
      q[i * 4 + 3] = v.w * 0.17677669529663687f;
    }
  }
  float mrun = -3.0e38f, lrun = 0.f;
  float acc[32];
#pragma unroll
  for (int i = 0; i < 32; ++i) acc[i] = 0.f;
  const int lr = tid >> 2, lc = (tid & 3) << 3;
  for (int kt = 0; kt < TENC; kt += 64) {
    {
      uint4 kw = *(const uint4*)(Kb + ((size_t)bh * TENC + kt + lr) * 32 + lc);
      Kl[lr][lc + 0] = bf2f_lo(kw.x); Kl[lr][lc + 1] = bf2f_hi(kw.x);
      Kl[lr][lc + 2] = bf2f_lo(kw.y); Kl[lr][lc + 3] = bf2f_hi(kw.y);
      Kl[lr][lc + 4] = bf2f_lo(kw.z); Kl[lr][lc + 5] = bf2f_hi(kw.z);
      Kl[lr][lc + 6] = bf2f_lo(kw.w); Kl[lr][lc + 7] = bf2f_hi(kw.w);
      uint4 vw = *(const uint4*)(Vb + ((size_t)bh * TENC + kt + lr) * 32 + lc);
      Vl[lr][lc + 0] = bf2f_lo(vw.x); Vl[lr][lc + 1] = bf2f_hi(vw.x);
      Vl[lr][lc + 2] = bf2f_lo(vw.y); Vl[lr][lc + 3] = bf2f_hi(vw.y);
      Vl[lr][lc + 4] = bf2f_lo(vw.z); Vl[lr][lc + 5] = bf2f_hi(vw.z);
      Vl[lr][lc + 6] = bf2f_lo(vw.w); Vl[lr][lc + 7] = bf2f_hi(vw.w);
    }
    __syncthreads();
#pragma unroll
    for (int cch = 0; cch < 8; ++cch) {
      float s8[8];
#pragma unroll
      for (int i = 0; i < 8; ++i) {
        const float4* kr = (const float4*)&Kl[cch * 8 + i][0];
        float ss = 0.f;
#pragma unroll
        for (int d4 = 0; d4 < 8; ++d4) {
          float4 kv = kr[d4];
          ss = fmaf(q[d4 * 4 + 0], kv.x, ss);
          ss = fmaf(q[d4 * 4 + 1], kv.y, ss);
          ss = fmaf(q[d4 * 4 + 2], kv.z, ss);
          ss = fmaf(q[d4 * 4 + 3], kv.w, ss);
        }
        s8[i] = ss;
      }
      float mnew = mrun;
#pragma unroll
      for (int i = 0; i < 8; ++i) mnew = fmaxf(mnew, s8[i]);
      float sc = __expf(mrun - mnew);
      mrun = mnew;
      lrun *= sc;
#pragma unroll
      for (int d = 0; d < 32; ++d) acc[d] *= sc;
#pragma unroll
      for (int i = 0; i < 8; ++i) {
        float p = __expf(s8[i] - mnew);
        lrun += p;
        const float4* vr = (const float4*)&Vl[cch * 8 + i][0];
#pragma unroll
        for (int d4 = 0; d4 < 8; ++d4) {
          float4 vv = vr[d4];
          acc[d4 * 4 + 0] = fmaf(p, vv.x, acc[d4 * 4 + 0]);
          acc[d4 * 4 + 1] = fmaf(p, vv.y, acc[d4 * 4 + 1]);
          acc[d4 * 4 + 2] = fmaf(p, vv.z, acc[d4 * 4 + 2]);
          acc[d4 * 4 + 3] = fmaf(p, vv.w, acc[d4 * 4 + 3]);
        }
      }
    }
    __syncthreads();
  }
  float inv = 1.0f / lrun;
  float* op = ctx + ((size_t)(b * TDEC + tid) * 256 + h * 32);
#pragma unroll
  for (int i = 0; i < 8; ++i) {
    ((float4*)op)[i] = make_float4(acc[i * 4 + 0] * inv, acc[i * 4 + 1] * inv,
                                   acc[i * 4 + 2] * inv, acc[i * 4 + 3] * inv);
  }
}

// ---------------- final: LN(dec_seq + ctxo) @ W_out + b_out ----------------
__global__ __launch_bounds__(256)
void k_final(const float* __restrict__ dec_seq, const float* __restrict__ ctxo,
             const float* __restrict__ g, const float* __restrict__ bb,
             const float* __restrict__ Wout, const float* __restrict__ bout,
             float* __restrict__ out) {
  const int wv = threadIdx.x >> 6, lane = threadIdx.x & 63;
  const int row = blockIdx.x * 4 + wv;
  const size_t base = (size_t)row * 256 + lane * 4;
  float4 dv = *(const float4*)(dec_seq + base);
  float4 cv = *(const float4*)(ctxo + base);
  float v[4] = {dv.x + cv.x, dv.y + cv.y, dv.z + cv.z, dv.w + cv.w};
  float s = v[0] + v[1] + v[2] + v[3];
#pragma unroll
  for (int off = 32; off >= 1; off >>= 1) s += __shfl_xor(s, off, 64);
  float m = s * (1.0f / 256.0f);
  float d2 = 0.f;
#pragma unroll
  for (int i = 0; i < 4; ++i) { float d = v[i] - m; d2 += d * d; }
#pragma unroll
  for (int off = 32; off >= 1; off >>= 1) d2 += __shfl_xor(d2, off, 64);
  float rs = rsqrtf(d2 * (1.0f / 256.0f) + LNEPS);
  float4 g4 = *(const float4*)(g + lane * 4);
  float4 b4 = *(const float4*)(bb + lane * 4);
  float4 w4 = *(const float4*)(Wout + lane * 4);
  float mix0 = g4.x * (v[0] - m) * rs + b4.x;
  float mix1 = g4.y * (v[1] - m) * rs + b4.y;
  float mix2 = g4.z * (v[2] - m) * rs + b4.z;
  float mix3 = g4.w * (v[3] - m) * rs + b4.w;
  float p = mix0 * w4.x + mix1 * w4.y + mix2 * w4.z + mix3 * w4.w;
#pragma unroll
  for (int off = 32; off >= 1; off >>= 1) p += __shfl_xor(p, off, 64);
  if (lane == 0) out[row] = p + bout[0];
}

extern "C" void kernel_launch(void* const* d_in, const int* in_sizes, int n_in,
                              void* d_out, int out_size, void* d_ws, size_t ws_size,
                              hipStream_t stream) {
  const float* enc_in   = (const float*)d_in[0];
  const float* dec_in   = (const float*)d_in[1];
  const float* ln_enc_g = (const float*)d_in[2];
  const float* ln_enc_b = (const float*)d_in[3];
  const float* W_enc    = (const float*)d_in[4];
  const float* U_enc    = (const float*)d_in[5];
  const float* b_enc    = (const float*)d_in[6];
  const float* W_dec    = (const float*)d_in[7];
  const float* U_dec    = (const float*)d_in[8];
  const float* b_dec    = (const float*)d_in[9];
  const float* Wq = (const float*)d_in[10]; const float* bq = (const float*)d_in[11];
  const float* Wk = (const float*)d_in[12]; const float* bk = (const float*)d_in[13];
  const float* Wv = (const float*)d_in[14]; const float* bv = (const float*)d_in[15];
  const float* Wo = (const float*)d_in[16]; const float* bo = (const float*)d_in[17];
  const float* ln_post_g = (const float*)d_in[18];
  const float* ln_post_b = (const float*)d_in[19];
  const float* W_out     = (const float*)d_in[20];
  const float* b_out     = (const float*)d_in[21];

  char* ws = (char*)d_ws;
  size_t off = 0;
  auto alloc = [&](size_t bytes) -> void* {
    void* p = ws + off;
    off += (bytes + 255) & ~(size_t)255;
    return p;
  };
  float* xln     = (float*)alloc((size_t)NBATCH * TENC * 8 * 4);
  uint4* upkE    = (uint4*)alloc((size_t)132 * 256 * 16);
  uint4* upkD    = (uint4*)alloc((size_t)132 * 256 * 16);
  float* enc_seq = (float*)alloc((size_t)NBATCH * TENC * 256 * 4);
  float* dec_seq = (float*)alloc((size_t)NBATCH * TDEC * 256 * 4);
  float* hfin    = (float*)alloc((size_t)NBATCH * 256 * 4);
  float* cfin    = (float*)alloc((size_t)NBATCH * 256 * 4);
  float* Qp      = (float*)alloc((size_t)NBATCH * NHEAD * TDEC * 32 * 4);
  u16*   Kb      = (u16*)  alloc((size_t)NBATCH * NHEAD * TENC * 32 * 2);
  u16*   Vb      = (u16*)  alloc((size_t)NBATCH * NHEAD * TENC * 32 * 2);
  float* ctx     = (float*)alloc((size_t)NBATCH * TDEC * 256 * 4);
  float* ctxo    = (float*)alloc((size_t)NBATCH * TDEC * 256 * 4);

  // 1. LN on encoder input
  k_ln8<<<dim3(256), dim3(256), 0, stream>>>(enc_in, ln_enc_g, ln_enc_b, xln,
                                             NBATCH * TENC);
  // 2. pack [U;W] -> per-unit gate-quad f16 pairs
  k_packUW2<<<dim3(132), dim3(256), 0, stream>>>(U_enc, W_enc, upkE);
  k_packUW2<<<dim3(132), dim3(256), 0, stream>>>(U_dec, W_dec, upkD);
  // 3. encoder scan
  k_scan4<<<dim3(NBATCH), dim3(1024), 0, stream>>>(
      xln, upkE, b_enc, nullptr, nullptr, enc_seq, hfin, cfin, TENC);
  // 4. decoder scan
  k_scan4<<<dim3(NBATCH), dim3(1024), 0, stream>>>(
      dec_in, upkD, b_dec, hfin, cfin, dec_seq, nullptr, nullptr, TDEC);
  // 5. projections
  k_gemm256<1><<<dim3(256, 4), dim3(256), 0, stream>>>(dec_seq, Wq, bq, Qp, NBATCH * TDEC, TDEC);
  k_gemm256<2><<<dim3(1024, 4), dim3(256), 0, stream>>>(enc_seq, Wk, bk, Kb, NBATCH * TENC, TENC);
  k_gemm256<2><<<dim3(1024, 4), dim3(256), 0, stream>>>(enc_seq, Wv, bv, Vb, NBATCH * TENC, TENC);
  // 6. attention
  k_attn<<<dim3(NBATCH * NHEAD), dim3(256), 0, stream>>>(Qp, Kb, Vb, ctx);
  // 7. output projection
  k_gemm256<0><<<dim3(256, 4), dim3(256), 0, stream>>>(ctx, Wo, bo, ctxo, NBATCH * TDEC, 0x7fffffff);
  // 8. residual + LN + final dot
  k_final<<<dim3(NBATCH * TDEC / 4), dim3(256), 0, stream>>>(
      dec_seq, ctxo, ln_post_g, ln_post_b, W_out, b_out, (float*)d_out);
}